// Round 10
// baseline (165.489 us; speedup 1.0000x reference)
//
#include <hip/hip_runtime.h>

// CP-decomposed 3D conv (AirConv3D): B=1, Cin=32, Cout=64, 56^3, K=3, pad=1, rank=53.
// All-f32. History: R13 two-phase 54us; R14 (512,4)=VGPR64 clamp -> spill blowup;
// R15 (512,2)=VGPR128, 16 waves/CU -> 84us; R16 k3c chunked two-phase 43us
// (VALUBusy 27%, HBM 21% -> stall-bound at barriers); R17 k1d pin+2split ~40us.
// LESSON (launch_bounds on this toolchain): 2nd arg ~ min blocks/CU.
// R18:
//  k3r: NO-LDS, NO-BARRIER k3. acc[64] f32 per thread (self-sufficient);
//       per rank: 9 loads + blend + 64 FMA (7:1 FMA:load). unroll 2 pipelines
//       rank r+1 loads under rank r FMAs. Grid 686x256 (2.7 waves/SIMD is the
//       binder, VGPR ~95 no clamp). Floor ~15-20us.
//  k1d: 4 partial accs (dep chain 32 -> 8) + 4-way rank split (12544 waves =
//       full residency). xv pinned via asm (R17).
// Go/no-go: k3r WRITE == 43904 KB exactly (no spill); k1d 20-28us.
// NOTE: one ~43us fillBuffer (268MB ws re-poison) sits in the timed window.
// Pipeline: k0_t -> k1d -> k3r. Fallback (small ws): R5 pipeline (known good).

#define NP 175616   // 56*56*56
#define HSTR 3136   // 56*56
#define CIN 32
#define RK 53
#define COUT 64
#define SCR 53      // fallback scratch slice base in d_out

// ---- k0: Ut[r*32+c] = Ucin[c*53+r] ----
__global__ __launch_bounds__(256) void k0_t(const float* __restrict__ Ucin,
                                            float* __restrict__ Ut)
{
    int t = blockIdx.x * 256 + threadIdx.x;
    if (t < RK * CIN) {
        int r = t >> 5, c = t & 31;
        Ut[t] = Ucin[c * RK + r];
    }
}

// ---- k1d: T1d[r,p] = d-conv(sum_c x[c,p]*Ut[r][c]) via wave shfl ----
// Block = 4 waves; wave = one (h,w) row (lanes 0..55 = d). blockIdx.y = rank
// quarter. 4 partial accs break the 32-deep dependent FMA chain.
__global__ __launch_bounds__(256) void k1d(
    const float* __restrict__ x, const float* __restrict__ Ut,
    const float* __restrict__ Ukd, float* __restrict__ T1d)
{
    const int lane = threadIdx.x & 63;          // d index
    const int row  = blockIdx.x * 4 + (threadIdx.x >> 6);   // (h,w) row in [0,3136)
    const int p    = row * 56 + lane;
    const bool act = (lane < 56);
    const int pc   = act ? p : (p - 8);         // clamp: lanes 56..63 in-bounds

    float xv[CIN];
#pragma unroll
    for (int c = 0; c < CIN; ++c) xv[c] = x[c * NP + pc];
#pragma unroll
    for (int c = 0; c < CIN; ++c) asm volatile("" : "+v"(xv[c]));  // pin in VGPRs

    // rank quarters: [0,14) [14,27) [27,40) [40,53)
    const int ry = blockIdx.y;
    const int r0 = (ry == 0) ? 0 : (14 + 13 * (ry - 1));
    const int r1 = (ry == 0) ? 14 : (r0 + 13);

#pragma unroll 2
    for (int r = r0; r < r1; ++r) {
        const float* U = Ut + r * CIN;          // uniform -> s_load
        float a0 = 0.f, a1 = 0.f, a2 = 0.f, a3 = 0.f;
#pragma unroll
        for (int c = 0; c < CIN; c += 4) {
            a0 += xv[c]     * U[c];
            a1 += xv[c + 1] * U[c + 1];
            a2 += xv[c + 2] * U[c + 2];
            a3 += xv[c + 3] * U[c + 3];
        }
        float acc = (a0 + a1) + (a2 + a3);
        // d-conv: out[d] = in[d-1]*kd0 + in[d]*kd1 + in[d+1]*kd2, zero pad
        float lm = __shfl_up(acc, 1, 64);
        float rp = __shfl_down(acc, 1, 64);
        if (lane == 0)  lm = 0.f;
        if (lane == 55) rp = 0.f;
        float res = lm * Ukd[r] + acc * Ukd[RK + r] + rp * Ukd[2 * RK + r];
        if (act) T1d[(size_t)r * NP + p] = res;
    }
}

// ---- k3r: no-LDS w+h conv + 53->64 projection + bias ----
// Each thread owns one point q and all 64 out-channels. Per rank: 9 boundary-
// clamped loads, w/h blend, 64 FMA into acc[]. No barriers -> loads of rank
// r+1 overlap FMAs of rank r (unroll 2).
__global__ __launch_bounds__(256) void k3r(
    const float* __restrict__ Ta, const float* __restrict__ Ucout,
    const float* __restrict__ bias, const float* __restrict__ Ukh,
    const float* __restrict__ Ukw, float* __restrict__ Out)
{
    // bijective XCD swizzle (m204); nwg = 686
    const int nwg = gridDim.x;
    const int qx = nwg >> 3, rx = nwg & 7;
    const int xcd = blockIdx.x & 7, loc = blockIdx.x >> 3;
    const int swz = ((xcd < rx) ? xcd * (qx + 1) : rx * (qx + 1) + (xcd - rx) * qx) + loc;

    const int q  = swz * 256 + threadIdx.x;      // point in [0,NP)
    const int h  = q / HSTR;
    const int rm = q - h * HSTR;
    const int w  = rm / 56;
    // boundary -> address select + 0/1 weight masks (branchless)
    const int om = (h > 0)  ? -HSTR : 0;
    const int op = (h < 55) ?  HSTR : 0;
    const int oa = (w > 0)  ? -56 : 0;
    const int oc = (w < 55) ?  56 : 0;
    const float mh0 = (h > 0)  ? 1.f : 0.f;
    const float mh2 = (h < 55) ? 1.f : 0.f;
    const float mw0 = (w > 0)  ? 1.f : 0.f;
    const float mw2 = (w < 55) ? 1.f : 0.f;

    const float* Sq = Ta + q;

    float acc[COUT];
#pragma unroll
    for (int o = 0; o < COUT; ++o) acc[o] = bias[o];

#pragma unroll 2
    for (int r = 0; r < RK; ++r) {
        const float* S = Sq + (size_t)r * NP;
        const float kw0 = mw0 * Ukw[r];
        const float kw1 = Ukw[RK + r];
        const float kw2 = mw2 * Ukw[2 * RK + r];
        const float kh0 = mh0 * Ukh[r];
        const float kh1 = Ukh[RK + r];
        const float kh2 = mh2 * Ukh[2 * RK + r];

        float v00 = S[om + oa], v01 = S[om], v02 = S[om + oc];
        float v10 = S[oa],      v11 = S[0],  v12 = S[oc];
        float v20 = S[op + oa], v21 = S[op], v22 = S[op + oc];

        float t = (v00 * kw0 + v01 * kw1 + v02 * kw2) * kh0
                + (v10 * kw0 + v11 * kw1 + v12 * kw2) * kh1
                + (v20 * kw0 + v21 * kw1 + v22 * kw2) * kh2;

        const float* Ur = Ucout + r * COUT;      // uniform -> s_load
#pragma unroll
        for (int o = 0; o < COUT; ++o) acc[o] += t * Ur[o];
    }

#pragma unroll
    for (int o = 0; o < COUT; ++o)
        Out[(size_t)o * NP + q] = acc[o];
}

// ===================== fallback path (R5, known good) =====================

__global__ __launch_bounds__(256) void k1_chunk(
    const float* __restrict__ x, const float* __restrict__ Ucin,
    float* T, int r0, int nr)
{
    __shared__ float sU[11 * CIN];
    const int tid = threadIdx.x;
    for (int t = tid; t < nr * CIN; t += 256) {
        int lr = t >> 5, c = t & 31;
        sU[t] = Ucin[c * RK + (r0 + lr)];
    }
    __syncthreads();
    const int p = blockIdx.x * 256 + tid;
    float xv[CIN];
#pragma unroll
    for (int c = 0; c < CIN; ++c) xv[c] = x[c * NP + p];
#pragma unroll 1
    for (int lr = 0; lr < nr; ++lr) {
        float acc = 0.f;
#pragma unroll
        for (int c = 0; c < CIN; ++c) acc += xv[c] * sU[lr * CIN + c];
        T[(size_t)(SCR + lr) * NP + p] = acc;
    }
}

__global__ __launch_bounds__(256) void k2_chunk(
    const float* __restrict__ Ukh, const float* __restrict__ Ukw,
    const float* __restrict__ Ukd, float* T, int r0)
{
    __shared__ float sIn[5800];
    __shared__ float sA[5600];
    const int lr = blockIdx.z;
    const int r  = r0 + lr;
    const int h0 = blockIdx.x * 8, w0 = blockIdx.y * 8;
    const int tid = threadIdx.x;
    const float kh0 = Ukh[r], kh1 = Ukh[RK + r], kh2 = Ukh[2 * RK + r];
    const float kw0 = Ukw[r], kw1 = Ukw[RK + r], kw2 = Ukw[2 * RK + r];
    const float kd0 = Ukd[r], kd1 = Ukd[RK + r], kd2 = Ukd[2 * RK + r];
    const float* T1r = T + (size_t)(SCR + lr) * NP;

    for (int idx = tid; idx < 5800; idx += 256) {
        int d = idx % 58; int t2 = idx / 58; int ww = t2 % 10; int hh = t2 / 10;
        int gh = h0 + hh - 1, gw = w0 + ww - 1, gd = d - 1;
        float v = 0.f;
        if ((unsigned)gh < 56u && (unsigned)gw < 56u && (unsigned)gd < 56u)
            v = T1r[gh * HSTR + gw * 56 + gd];
        sIn[idx] = v;
    }
    __syncthreads();
    for (int idx = tid; idx < 5600; idx += 256) {
        int d = idx % 56; int t2 = idx / 56; int ww = t2 % 10; int hh = t2 / 10;
        const float* b = &sIn[(hh * 10 + ww) * 58 + d];
        sA[idx] = b[0] * kd0 + b[1] * kd1 + b[2] * kd2;
    }
    __syncthreads();
    const float k00 = kh0 * kw0, k01 = kh0 * kw1, k02 = kh0 * kw2;
    const float k10 = kh1 * kw0, k11 = kh1 * kw1, k12 = kh1 * kw2;
    const float k20 = kh2 * kw0, k21 = kh2 * kw1, k22 = kh2 * kw2;
    for (int idx = tid; idx < 3584; idx += 256) {
        int d = idx % 56; int t2 = idx / 56; int ww = t2 % 8; int hh = t2 / 8;
        const float* a = &sA[(hh * 10 + ww) * 56 + d];
        float acc = a[0]    * k00 + a[56]   * k01 + a[112]  * k02
                  + a[560]  * k10 + a[616]  * k11 + a[672]  * k12
                  + a[1120] * k20 + a[1176] * k21 + a[1232] * k22;
        T[(size_t)r * NP + (h0 + hh) * HSTR + (w0 + ww) * 56 + d] = acc;
    }
}

__global__ __launch_bounds__(256) void k3_out(
    float* T, const float* __restrict__ Ucout, const float* __restrict__ bias)
{
    __shared__ float sUo[RK * COUT];
    __shared__ float sB[COUT];
    const int tid = threadIdx.x;
    for (int t = tid; t < RK * COUT; t += 256) sUo[t] = Ucout[t];
    if (tid < COUT) sB[tid] = bias[tid];
    __syncthreads();
    const int p = blockIdx.x * 256 + tid;
    float acc[COUT];
#pragma unroll
    for (int o = 0; o < COUT; ++o) acc[o] = sB[o];
#pragma unroll 1
    for (int r = 0; r < RK; ++r) {
        float t = T[(size_t)r * NP + p];
        const float* Ur = &sUo[r * COUT];
#pragma unroll
        for (int o = 0; o < COUT; ++o) acc[o] += t * Ur[o];
    }
#pragma unroll
    for (int o = 0; o < COUT; ++o) T[(size_t)o * NP + p] = acc[o];
}

// ===================== launch =====================

extern "C" void kernel_launch(void* const* d_in, const int* in_sizes, int n_in,
                              void* d_out, int out_size, void* d_ws, size_t ws_size,
                              hipStream_t stream)
{
    const float* x     = (const float*)d_in[0];
    const float* Ukh   = (const float*)d_in[1];
    const float* Ukw   = (const float*)d_in[2];
    const float* Ukd   = (const float*)d_in[3];
    const float* Ucin  = (const float*)d_in[4];
    const float* Ucout = (const float*)d_in[5];
    const float* bias  = (const float*)d_in[6];

    const size_t t1_bytes = (size_t)RK * NP * sizeof(float);   // 37.2 MB

    if (ws_size >= t1_bytes + 8192) {
        float* T1 = (float*)d_ws;
        float* Ut = (float*)((char*)d_ws + t1_bytes);          // 6.8 KB
        k0_t<<<7, 256, 0, stream>>>(Ucin, Ut);
        k1d<<<dim3(HSTR / 4, 4), 256, 0, stream>>>(x, Ut, Ukd, T1);  // 3136 blocks
        k3r<<<NP / 256, 256, 0, stream>>>(T1, Ucout, bias, Ukh,
                                          Ukw, (float*)d_out);       // 686 blocks
    } else {
        float* T = (float*)d_out;
        for (int r0 = 0; r0 < RK; r0 += 11) {
            int nr = (RK - r0 < 11) ? (RK - r0) : 11;
            k1_chunk<<<NP / 256, 256, 0, stream>>>(x, Ucin, T, r0, nr);
            k2_chunk<<<dim3(7, 7, nr), 256, 0, stream>>>(Ukh, Ukw, Ukd, T, r0);
        }
        k3_out<<<NP / 256, 256, 0, stream>>>(T, Ucout, bias);
    }
}